// Round 19
// baseline (41.384 us; speedup 1.0000x reference)
//
#include <hip/hip_runtime.h>

typedef _Float16 h2 __attribute__((ext_vector_type(2)));
typedef _Float16 h8 __attribute__((ext_vector_type(8)));
typedef float f4 __attribute__((ext_vector_type(4)));
typedef unsigned int uint32;

#define NVAL 20
#define CDIM 64
#define HW   65536
#define NPIX (4*HW)

#define BLK   1024
#define NWAVE 16
#define MAXTILES 35               // sum ceil(n_k/64) <= 34 for a 1024-px window
#define MSLOT (MAXTILES*64)

// ---- packed f16 tables in ws (bytes) ----
#define KN_OFF      0
#define KN_KSTRIDE  2560          // per class: 20 j-rows x 128 B (c-contig, normalized)
#define VAL_OFF     (20*KN_KSTRIDE)      // 51200
#define VAL_KSTRIDE 4096          // per class: 64 c-rows x 64 B (32 j-slots)
#define VAL_CSTRIDE 64

// ---- LDS layout (bytes) ----
// Pixel rows hold 16 uint2 "slots" (slot s = channels 4s..4s+3), stored
// SWIZZLED: physical byte = 8*((s + (pixel>>2)) & 15). This makes the
// stage/store consecutive-row scatter hit 32 distinct banks (2-way = free).
#define ROW_STRIDE 144
#define ROWS_BYTES (BLK*ROW_STRIDE)          // 147456
#define PERM_OFF  ROWS_BYTES                 // MSLOT u16 (4480)
#define TCLS_OFF  (PERM_OFF + MSLOT*2)       // MAXTILES int
#define CNT_OFF   (TCLS_OFF + MAXTILES*4 + 4)
#define LDS_TOTAL (CNT_OFF + 24*4 + 16)      // ~152.3 KB -> 1 block/CU

static __device__ __forceinline__ h2 bch2(uint32 u) { return __builtin_bit_cast(h2, u); }
static __device__ __forceinline__ uint32 bcu(h2 v) { return __builtin_bit_cast(uint32, v); }
static __device__ __forceinline__ h8 bch8(uint4 u) { return __builtin_bit_cast(h8, u); }
static __device__ __forceinline__ h2 pkrtz(float a, float b) {
    return __builtin_bit_cast(h2, __builtin_amdgcn_cvt_pkrtz(a, b));
}
static __device__ __forceinline__ float dot2acc(h2 a, h2 b, float acc) {
#if defined(__has_builtin)
#if __has_builtin(__builtin_amdgcn_fdot2)
    return __builtin_amdgcn_fdot2(a, b, acc, false);
#else
    return acc + (float)a[0]*(float)b[0] + (float)a[1]*(float)b[1];
#endif
#else
    return acc + (float)a[0]*(float)b[0] + (float)a[1]*(float)b[1];
#endif
}

// ---------------------------------------------------------------------------
// Prep: build packed f16 tables in ws (unchanged, verified since round 5).
// ---------------------------------------------------------------------------
__global__ void prep_kernel(const float* __restrict__ key,
                            const float* __restrict__ val,
                            unsigned char* __restrict__ ws) {
    int i = blockIdx.x * 256 + threadIdx.x;
    if (i < 20*CDIM) {
        int k = i >> 6, c = i & 63;
        const float* vb = val + k*NVAL*CDIM + c;     // val[k][j][c]
        float v[NVAL];
        float s = 0.f;
        #pragma unroll
        for (int j = 0; j < NVAL; j++) { v[j] = vb[j*CDIM]; s += v[j]; }
        float t = 0.f;
        for (int kk = 0; kk < 20; kk++) {
            const float* vb2 = val + kk*NVAL*CDIM + c;
            #pragma unroll
            for (int j = 0; j < NVAL; j++) t += vb2[j*CDIM];
        }
        float rest = (t - s) * (1.0f/NVAL);
        uint32* row = (uint32*)(ws + VAL_OFF + (size_t)k*VAL_KSTRIDE + c*VAL_CSTRIDE);
        #pragma unroll
        for (int jp = 0; jp < 10; jp++) row[jp] = bcu(pkrtz(v[2*jp], v[2*jp+1]));
        row[10] = bcu(pkrtz(rest, 0.f));
        #pragma unroll
        for (int jp = 11; jp < 16; jp++) row[jp] = 0u;
    } else if (i < 20*CDIM + 20*NVAL) {
        int idx = i - 20*CDIM;
        int k = idx / NVAL, j = idx % NVAL;
        const float* kb = key + k*CDIM*NVAL + j;     // key[k][c][j]
        float x[CDIM];
        float ssq = 0.f;
        #pragma unroll
        for (int c = 0; c < CDIM; c++) { x[c] = kb[c*NVAL]; ssq = fmaf(x[c], x[c], ssq); }
        float inv = 1.0f / fmaxf(sqrtf(ssq), 1e-12f);
        uint32* row = (uint32*)(ws + KN_OFF + (size_t)k*KN_KSTRIDE + j*128);
        #pragma unroll
        for (int cp = 0; cp < 32; cp++) row[cp] = bcu(pkrtz(x[2*cp]*inv, x[2*cp+1]*inv));
    }
}

// every thread redundantly scans the 20 counters: {my_base_slot, n_tiles}
static __device__ __forceinline__ int2 scan20(const int* cnt, int cls) {
    int acc = 0, mb = 0;
    #pragma unroll
    for (int k = 1; k <= 20; k++) {
        if (k == cls) mb = acc;
        acc += (cnt[k] + 63) & ~63;
    }
    return make_int2(mb, acc >> 6);
}

// ---------------------------------------------------------------------------
// Main: 256 blocks x 1024 threads (1 block/CU). ALL global I/O is contiguous
// dwordx4 streams (4 KB per channel-plane chunk): wave w owns channels
// 4w..4w+3 for both stage and store; the pixel<->channel transpose happens in
// LDS via slot-swizzled uint2 scatter (2-way banks). Middle = r15-verbatim
// class-sorted 64-px wave-tiles, with inv computed in-register from the
// fragments (no invA pass).
// ---------------------------------------------------------------------------
__global__ __launch_bounds__(BLK) void main_kernel(
        const float* __restrict__ content, const int* __restrict__ seg,
        const unsigned char* __restrict__ tabs, float* __restrict__ out) {
    extern __shared__ unsigned char lds[];
    unsigned short* perm = (unsigned short*)(lds + PERM_OFF);
    int* tcls = (int*)(lds + TCLS_OFF);
    int* cnt  = (int*)(lds + CNT_OFF);

    const int tid  = threadIdx.x;
    const int wave = tid >> 6, lane = tid & 63;
    const int g = lane >> 4, r16 = lane & 15;
    const int bid  = (int)((blockIdx.x & 7) * 32 + (blockIdx.x >> 3));  // XCD swizzle
    const int gp0  = bid * BLK;
    const int b    = gp0 >> 16;
    const int pim0 = gp0 & (HW - 1);

    if (tid < 24) cnt[tid] = 0;
    for (int i = tid; i < MSLOT; i += BLK) perm[i] = 0xFFFFu;   // r18 bugfix: REQUIRED
    __syncthreads();

    const int cls = seg[gp0 + tid] + 1;          // 1..19
    const int myrank = atomicAdd(&cnt[cls], 1);

    // ---- stage: contiguous dwordx4 loads, transpose via swizzled LDS scatter ----
    {
        const float* cb = content + (size_t)b * CDIM * HW
                          + (size_t)(4*wave) * HW + pim0 + 4*lane;
        f4 x0[4], x1[4], x2[4], x3[4];
        #pragma unroll
        for (int j = 0; j < 4; j++) x0[j] = *(const f4*)(cb + 0*(size_t)HW + j*256);
        #pragma unroll
        for (int j = 0; j < 4; j++) x1[j] = *(const f4*)(cb + 1*(size_t)HW + j*256);
        #pragma unroll
        for (int j = 0; j < 4; j++) x2[j] = *(const f4*)(cb + 2*(size_t)HW + j*256);
        #pragma unroll
        for (int j = 0; j < 4; j++) x3[j] = *(const f4*)(cb + 3*(size_t)HW + j*256);

        const int woff = 8 * ((wave + lane) & 15);   // swizzled slot byte offset
        #pragma unroll
        for (int j = 0; j < 4; j++) {
            unsigned char* rb = lds + (j*256 + 4*lane) * ROW_STRIDE + woff;
            #pragma unroll
            for (int i = 0; i < 4; i++) {
                uint2 o;
                o.x = bcu(pkrtz(x0[j][i], x1[j][i]));
                o.y = bcu(pkrtz(x2[j][i], x3[j][i]));
                *(uint2*)(rb + i*ROW_STRIDE) = o;
            }
        }
    }
    __syncthreads();                              // rows + histogram complete

    const int2 s = scan20(cnt, cls);              // (my base slot, n tiles)
    {
        int slot = s.x + myrank;
        perm[slot] = (unsigned short)tid;
        tcls[slot >> 6] = cls;                    // class-pure tile
    }
    __syncthreads();                              // perm/tcls complete

    const int nt = s.y;

    for (int t = wave; t < nt; t += NWAVE) {
        const int u = __builtin_amdgcn_readfirstlane(tcls[t]);

        int rowb[4], q4[4];
        bool mine[4];
        #pragma unroll
        for (int n = 0; n < 4; n++) {
            int v = perm[t*64 + n*16 + r16];
            mine[n] = (v != 0xFFFF);
            int l = mine[n] ? v : 0;
            rowb[n] = l * ROW_STRIDE;
            q4[n] = (l >> 2) & 15;
        }

        // ---- table loads up front (named regs) ----
        const unsigned char* knc = tabs + KN_OFF + (size_t)u * KN_KSTRIDE;
        const unsigned char* vc  = tabs + VAL_OFF + (size_t)u * VAL_KSTRIDE;
        uint4 a_sc[2][2];
        #pragma unroll
        for (int m = 0; m < 2; m++)
            #pragma unroll
            for (int ks = 0; ks < 2; ks++)
                a_sc[m][ks] = *(const uint4*)(knc + (m*16 + r16)*128 + (ks*32 + g*8)*2);
        uint4 apv0 = *(const uint4*)(vc + (0*16 + r16)*VAL_CSTRIDE + g*16);
        uint4 apv1 = *(const uint4*)(vc + (1*16 + r16)*VAL_CSTRIDE + g*16);
        uint4 apv2 = *(const uint4*)(vc + (2*16 + r16)*VAL_CSTRIDE + g*16);
        uint4 apv3 = *(const uint4*)(vc + (3*16 + r16)*VAL_CSTRIDE + g*16);

        // ---- X fragments from swizzled slots (2x b64 per ks) + in-reg ssq ----
        uint4 b_sc[4][2];
        float invn[4];
        #pragma unroll
        for (int n = 0; n < 4; n++) {
            const unsigned char* rp = lds + rowb[n];
            #pragma unroll
            for (int ks = 0; ks < 2; ks++) {
                int s0 = 8*ks + 2*g;
                uint2 lo = *(const uint2*)(rp + 8*((s0 + q4[n]) & 15));
                uint2 hi = *(const uint2*)(rp + 8*((s0 + 1 + q4[n]) & 15));
                uint4 f; f.x = lo.x; f.y = lo.y; f.z = hi.x; f.w = hi.y;
                b_sc[n][ks] = f;
            }
            float ss = 0.f;
            #pragma unroll
            for (int ks = 0; ks < 2; ks++) {
                uint4 f = b_sc[n][ks];
                ss = dot2acc(bch2(f.x), bch2(f.x), ss);
                ss = dot2acc(bch2(f.y), bch2(f.y), ss);
                ss = dot2acc(bch2(f.z), bch2(f.z), ss);
                ss = dot2acc(bch2(f.w), bch2(f.w), ss);
            }
            ss += __shfl_xor(ss, 16, 64);
            ss += __shfl_xor(ss, 32, 64);
            invn[n] = 1.0f / fmaxf(sqrtf(ss), 1e-12f);
        }

        // ---- scores S^T[j][p] = sum_c Kn^T[j][c] * X^T[c][p] ----
        f4 sacc[2][4];
        #pragma unroll
        for (int m = 0; m < 2; m++)
            #pragma unroll
            for (int n = 0; n < 4; n++) sacc[m][n] = (f4){0.f,0.f,0.f,0.f};
        #pragma unroll
        for (int ks = 0; ks < 2; ks++)
            #pragma unroll
            for (int m = 0; m < 2; m++)
                #pragma unroll
                for (int n = 0; n < 4; n++)
                    sacc[m][n] = __builtin_amdgcn_mfma_f32_16x16x32_f16(
                        bch8(a_sc[m][ks]), bch8(b_sc[n][ks]), sacc[m][n], 0, 0, 0);

        // ---- softmax; lane holds j = m*16 + g*4 + r for pixel p = n*16+r16 ----
        uint2 w0[4], w1[4];
        #pragma unroll
        for (int n = 0; n < 4; n++) {
            float e0[4], e1[4];
            #pragma unroll
            for (int r = 0; r < 4; r++) e0[r] = __expf(sacc[0][n][r] * invn[n]);
            float arg1 = (g == 0) ? invn[n] : 0.0f;     // j>=20 masked
            #pragma unroll
            for (int r = 0; r < 4; r++) e1[r] = __expf(sacc[1][n][r] * arg1);
            float sum = e0[0]+e0[1]+e0[2]+e0[3];
            sum += (g == 0) ? (e1[0]+e1[1]+e1[2]+e1[3]) : 0.0f;
            sum += __shfl_xor(sum, 16, 64);
            sum += __shfl_xor(sum, 32, 64);
            float wsc = 1.0f / sum;
            w0[n].x = bcu(pkrtz(e0[0]*wsc, e0[1]*wsc));
            w0[n].y = bcu(pkrtz(e0[2]*wsc, e0[3]*wsc));
            uint2 t1;
            if (g == 0)      { t1.x = bcu(pkrtz(e1[0]*wsc, e1[1]*wsc));
                               t1.y = bcu(pkrtz(e1[2]*wsc, e1[3]*wsc)); }
            else if (g == 1) { t1.x = 0x00003C00u; t1.y = 0u; }  // j20=1.0 (rest)
            else             { t1.x = 0u; t1.y = 0u; }
            w1[n] = t1;
        }
        // write W over own row's first 64 bytes (plain slots; X fully consumed)
        #pragma unroll
        for (int n = 0; n < 4; n++) {
            if (mine[n]) {
                *(uint2*)(lds + rowb[n] + g*8)      = w0[n];
                *(uint2*)(lds + rowb[n] + 32 + g*8) = w1[n];
            }
        }

        // ---- PV O^T[c][p] = sum_j V^T[c][j] * W^T[j][p] (K=32) ----
        uint4 b_pv[4];
        #pragma unroll
        for (int n = 0; n < 4; n++)
            b_pv[n] = *(const uint4*)(lds + rowb[n] + g*16);
        #pragma unroll
        for (int m = 0; m < 4; m++) {
            uint4 a = (m == 0) ? apv0 : (m == 1) ? apv1 : (m == 2) ? apv2 : apv3;
            #pragma unroll
            for (int n = 0; n < 4; n++) {
                f4 o = (f4){0.f,0.f,0.f,0.f};
                o = __builtin_amdgcn_mfma_f32_16x16x32_f16(bch8(a), bch8(b_pv[n]), o, 0, 0, 0);
                uint2 ov; ov.x = bcu(pkrtz(o[0], o[1])); ov.y = bcu(pkrtz(o[2], o[3]));
                if (mine[n])   // O slot s = 4m+g, swizzled by pixel
                    *(uint2*)(lds + rowb[n] + 8*((4*m + g + q4[n]) & 15)) = ov;
            }
        }
    }
    __syncthreads();                              // all tiles complete

    // ---- store: swizzled LDS gather -> contiguous dwordx4 streams ----
    {
        const int woff = 8 * ((wave + lane) & 15);
        float* ob = out + (size_t)b * CDIM * HW + (size_t)(4*wave) * HW + pim0 + 4*lane;
        #pragma unroll
        for (int j = 0; j < 4; j++) {
            const unsigned char* rb = lds + (j*256 + 4*lane) * ROW_STRIDE + woff;
            f4 v0, v1, v2, v3;
            #pragma unroll
            for (int i = 0; i < 4; i++) {
                uint2 u = *(const uint2*)(rb + i*ROW_STRIDE);
                h2 a = bch2(u.x), c = bch2(u.y);
                v0[i] = (float)a[0];
                v1[i] = (float)a[1];
                v2[i] = (float)c[0];
                v3[i] = (float)c[1];
            }
            *(f4*)(ob + 0*(size_t)HW + j*256) = v0;
            *(f4*)(ob + 1*(size_t)HW + j*256) = v1;
            *(f4*)(ob + 2*(size_t)HW + j*256) = v2;
            *(f4*)(ob + 3*(size_t)HW + j*256) = v3;
        }
    }
}

extern "C" void kernel_launch(void* const* d_in, const int* in_sizes, int n_in,
                              void* d_out, int out_size, void* d_ws, size_t ws_size,
                              hipStream_t stream) {
    const float* content = (const float*)d_in[0];
    const int*   seg     = (const int*)d_in[1];
    const float* key     = (const float*)d_in[2];
    const float* val     = (const float*)d_in[3];
    float* out = (float*)d_out;
    unsigned char* ws = (unsigned char*)d_ws;

    prep_kernel<<<7, 256, 0, stream>>>(key, val, ws);

    (void)hipFuncSetAttribute((const void*)main_kernel,
                              hipFuncAttributeMaxDynamicSharedMemorySize, LDS_TOTAL);
    main_kernel<<<NPIX/BLK, BLK, LDS_TOTAL, stream>>>(content, seg, ws, out);
}

// Round 20
// 40.022 us; speedup vs baseline: 1.0340x; 1.0340x over previous
//
#include <hip/hip_runtime.h>

typedef _Float16 h2 __attribute__((ext_vector_type(2)));
typedef _Float16 h8 __attribute__((ext_vector_type(8)));
typedef float f4 __attribute__((ext_vector_type(4)));
typedef unsigned int uint32;

#define NVAL 20
#define CDIM 64
#define HW   65536
#define NPIX (4*HW)

#define BLK   1024
#define NWAVE 16
#define MAXTILES 35               // sum ceil(n_k/64) <= 34 for a 1024-px window
#define MSLOT (MAXTILES*64)

// ---- packed f16 tables in ws (bytes) ----
#define KN_OFF      0
#define KN_KSTRIDE  2560          // per class: 20 j-rows x 128 B (c-contig, normalized)
#define VAL_OFF     (20*KN_KSTRIDE)      // 51200
#define VAL_KSTRIDE 4096          // per class: 64 c-rows x 64 B (32 j-slots)
#define VAL_CSTRIDE 64

// ---- LDS layout (bytes) ----
#define ROW_STRIDE 144            // 64 f16 (128 B) + 16 pad; 16B-aligned rows
#define ROWS_BYTES (BLK*ROW_STRIDE)          // 147456
#define INV_OFF   ROWS_BYTES                 // BLK f32 (4096)
#define PERM_OFF  (INV_OFF + BLK*4)          // MSLOT u16 (4480)
#define TCLS_OFF  (PERM_OFF + MSLOT*2)
#define FLAG_OFF  (TCLS_OFF + 144)
#define CNT_OFF   (FLAG_OFF + 144)
#define LDS_TOTAL (CNT_OFF + 24*4 + 16)      // ~152.8 KB -> 1 block/CU

static __device__ __forceinline__ h2 bch2(uint32 u) { return __builtin_bit_cast(h2, u); }
static __device__ __forceinline__ uint32 bcu(h2 v) { return __builtin_bit_cast(uint32, v); }
static __device__ __forceinline__ h8 bch8(uint4 u) { return __builtin_bit_cast(h8, u); }
static __device__ __forceinline__ h2 pkrtz(float a, float b) {
    return __builtin_bit_cast(h2, __builtin_amdgcn_cvt_pkrtz(a, b));
}

// ---------------------------------------------------------------------------
// Prep: build packed f16 tables in ws (unchanged, verified since round 5).
// ---------------------------------------------------------------------------
__global__ void prep_kernel(const float* __restrict__ key,
                            const float* __restrict__ val,
                            unsigned char* __restrict__ ws) {
    int i = blockIdx.x * 256 + threadIdx.x;
    if (i < 20*CDIM) {
        int k = i >> 6, c = i & 63;
        const float* vb = val + k*NVAL*CDIM + c;     // val[k][j][c]
        float v[NVAL];
        float s = 0.f;
        #pragma unroll
        for (int j = 0; j < NVAL; j++) { v[j] = vb[j*CDIM]; s += v[j]; }
        float t = 0.f;
        for (int kk = 0; kk < 20; kk++) {
            const float* vb2 = val + kk*NVAL*CDIM + c;
            #pragma unroll
            for (int j = 0; j < NVAL; j++) t += vb2[j*CDIM];
        }
        float rest = (t - s) * (1.0f/NVAL);
        uint32* row = (uint32*)(ws + VAL_OFF + (size_t)k*VAL_KSTRIDE + c*VAL_CSTRIDE);
        #pragma unroll
        for (int jp = 0; jp < 10; jp++) row[jp] = bcu(pkrtz(v[2*jp], v[2*jp+1]));
        row[10] = bcu(pkrtz(rest, 0.f));
        #pragma unroll
        for (int jp = 11; jp < 16; jp++) row[jp] = 0u;
    } else if (i < 20*CDIM + 20*NVAL) {
        int idx = i - 20*CDIM;
        int k = idx / NVAL, j = idx % NVAL;
        const float* kb = key + k*CDIM*NVAL + j;     // key[k][c][j]
        float x[CDIM];
        float ssq = 0.f;
        #pragma unroll
        for (int c = 0; c < CDIM; c++) { x[c] = kb[c*NVAL]; ssq = fmaf(x[c], x[c], ssq); }
        float inv = 1.0f / fmaxf(sqrtf(ssq), 1e-12f);
        uint32* row = (uint32*)(ws + KN_OFF + (size_t)k*KN_KSTRIDE + j*128);
        #pragma unroll
        for (int cp = 0; cp < 32; cp++) row[cp] = bcu(pkrtz(x[2*cp]*inv, x[2*cp+1]*inv));
    }
}

// every thread redundantly scans the 20 counters: {my_base_slot, n_tiles}
static __device__ __forceinline__ int2 scan20(const int* cnt, int cls) {
    int acc = 0, mb = 0;
    #pragma unroll
    for (int k = 1; k <= 20; k++) {
        if (k == cls) mb = acc;
        acc += (cnt[k] + 63) & ~63;
    }
    return make_int2(mb, acc >> 6);
}

// ---------------------------------------------------------------------------
// Main: 256 blocks x 1024 threads (1 block/CU, 16 waves). Round-15 structure.
// Delta vs r15: the softmax->PV W handoff is done IN-REGISTER via 6 __shfl
// per subtile (4-lane-group permutation) instead of an LDS W-write + fence +
// b64 read -- shortens each tile's critical path and removes W bank traffic.
// s_setprio(1) wraps the per-tile compute (role-diverse waves: T5 regime).
// ---------------------------------------------------------------------------
__global__ __launch_bounds__(BLK) void main_kernel(
        const float* __restrict__ content, const int* __restrict__ seg,
        const unsigned char* __restrict__ tabs, float* __restrict__ out) {
    extern __shared__ unsigned char lds[];
    float* invA = (float*)(lds + INV_OFF);
    unsigned short* perm = (unsigned short*)(lds + PERM_OFF);
    int* tcls  = (int*)(lds + TCLS_OFF);
    int* flags = (int*)(lds + FLAG_OFF);
    int* cnt   = (int*)(lds + CNT_OFF);

    const int tid  = threadIdx.x;
    const int bid  = (int)((blockIdx.x & 7) * 32 + (blockIdx.x >> 3));  // XCD swizzle
    const int gp0  = bid * BLK;
    const int b    = gp0 >> 16;
    const int pim0 = gp0 & (HW - 1);
    float* obase = out + (size_t)b * CDIM * HW + pim0;

    if (tid < 24) cnt[tid] = 0;
    if (tid < MAXTILES) flags[tid] = 0;
    for (int i = tid; i < MSLOT; i += BLK) perm[i] = 0xFFFFu;
    __syncthreads();

    const int cls = seg[gp0 + tid] + 1;          // 1..19
    const int myrank = atomicAdd(&cnt[cls], 1);

    // stage content -> own LDS row (f16 pairs, unnormalized) + inv.
    {
        const float* cptr = content + (size_t)b * CDIM * HW + pim0 + tid;
        uint2* myrow = (uint2*)(lds + tid * ROW_STRIDE);
        float ssq = 0.f;
        #pragma unroll
        for (int h = 0; h < 2; h++) {
            float xb[32];
            #pragma unroll
            for (int j = 0; j < 32; j++) xb[j] = cptr[(size_t)(h*32 + j) * HW];
            #pragma unroll
            for (int j = 0; j < 32; j++) ssq = fmaf(xb[j], xb[j], ssq);
            #pragma unroll
            for (int q = 0; q < 8; q++) {
                uint2 o;
                o.x = bcu(pkrtz(xb[4*q+0], xb[4*q+1]));
                o.y = bcu(pkrtz(xb[4*q+2], xb[4*q+3]));
                myrow[h*8 + q] = o;
            }
        }
        invA[tid] = 1.0f / fmaxf(sqrtf(ssq), 1e-12f);
    }
    __syncthreads();                              // cnt + rows + inv complete

    const int2 s = scan20(cnt, cls);              // (my base slot, n tiles)
    const int myslot = s.x + myrank;
    const int mytile = myslot >> 6;
    {
        perm[myslot] = (unsigned short)tid;
        tcls[mytile] = cls;                       // class-pure tile
    }
    __syncthreads();                              // perm/tcls complete

    const int nt   = s.y;
    const int wave = tid >> 6, lane = tid & 63;
    const int g = lane >> 4, r16 = lane & 15;

    for (int t = wave; t < nt; t += NWAVE) {
        const int u = __builtin_amdgcn_readfirstlane(tcls[t]);

        int rowb[4];
        float invn[4];
        bool mine[4];
        #pragma unroll
        for (int n = 0; n < 4; n++) {
            int v = perm[t*64 + n*16 + r16];
            mine[n] = (v != 0xFFFF);
            int l = mine[n] ? v : 0;
            rowb[n] = l * ROW_STRIDE;
            invn[n] = invA[l];
        }

        // ---- issue ALL table loads for this tile up front (named regs) ----
        const unsigned char* knc = tabs + KN_OFF + (size_t)u * KN_KSTRIDE;
        const unsigned char* vc  = tabs + VAL_OFF + (size_t)u * VAL_KSTRIDE;
        uint4 a_sc[2][2];
        #pragma unroll
        for (int m = 0; m < 2; m++)
            #pragma unroll
            for (int ks = 0; ks < 2; ks++)
                a_sc[m][ks] = *(const uint4*)(knc + (m*16 + r16)*128 + (ks*32 + g*8)*2);
        uint4 apv0 = *(const uint4*)(vc + (0*16 + r16)*VAL_CSTRIDE + g*16);
        uint4 apv1 = *(const uint4*)(vc + (1*16 + r16)*VAL_CSTRIDE + g*16);
        uint4 apv2 = *(const uint4*)(vc + (2*16 + r16)*VAL_CSTRIDE + g*16);
        uint4 apv3 = *(const uint4*)(vc + (3*16 + r16)*VAL_CSTRIDE + g*16);

        uint4 b_sc[4][2];
        #pragma unroll
        for (int n = 0; n < 4; n++)
            #pragma unroll
            for (int ks = 0; ks < 2; ks++)
                b_sc[n][ks] = *(const uint4*)(lds + rowb[n] + (ks*32 + g*8)*2);

        __builtin_amdgcn_s_setprio(1);

        // ---- scores S^T[j][p] = sum_c Kn^T[j][c] * X^T[c][p] ----
        f4 sacc[2][4];
        #pragma unroll
        for (int m = 0; m < 2; m++)
            #pragma unroll
            for (int n = 0; n < 4; n++) sacc[m][n] = (f4){0.f,0.f,0.f,0.f};
        #pragma unroll
        for (int ks = 0; ks < 2; ks++)
            #pragma unroll
            for (int m = 0; m < 2; m++)
                #pragma unroll
                for (int n = 0; n < 4; n++)
                    sacc[m][n] = __builtin_amdgcn_mfma_f32_16x16x32_f16(
                        bch8(a_sc[m][ks]), bch8(b_sc[n][ks]), sacc[m][n], 0, 0, 0);

        // ---- softmax + IN-REGISTER W redistribution (no LDS round trip) ----
        // lane (g,r16) holds j = m*16 + g*4 + r for pixel column (n, r16).
        // PV B-frag for lane (g,r16): j = g*8..g*8+7 of the same pixel, built
        // from the 4 g-lanes of that pixel via __shfl + constants (j20=rest).
        uint4 bpv[4];
        #pragma unroll
        for (int n = 0; n < 4; n++) {
            float e0[4], e1[4];
            #pragma unroll
            for (int r = 0; r < 4; r++) e0[r] = __expf(sacc[0][n][r] * invn[n]);
            float arg1 = (g == 0) ? invn[n] : 0.0f;     // only g'=0's e1 (j16-19) is real
            #pragma unroll
            for (int r = 0; r < 4; r++) e1[r] = __expf(sacc[1][n][r] * arg1);
            float sum = e0[0]+e0[1]+e0[2]+e0[3];
            sum += (g == 0) ? (e1[0]+e1[1]+e1[2]+e1[3]) : 0.0f;
            sum += __shfl_xor(sum, 16, 64);
            sum += __shfl_xor(sum, 32, 64);
            float wsc = 1.0f / sum;
            uint32 pk0 = bcu(pkrtz(e0[0]*wsc, e0[1]*wsc));   // j = g*4 + {0,1}
            uint32 pk1 = bcu(pkrtz(e0[2]*wsc, e0[3]*wsc));   // j = g*4 + {2,3}
            uint32 pk2 = bcu(pkrtz(e1[0]*wsc, e1[1]*wsc));   // j = 16+g*4+{0,1} (real @ g=0)
            uint32 pk3 = bcu(pkrtz(e1[2]*wsc, e1[3]*wsc));
            int selA = r16 + ((g == 1) ? 32 : 0);            // g=0: g'=0 ; g=1: g'=2
            int selB = r16 + ((g == 1) ? 48 : 16);           // g=0: g'=1 ; g=1: g'=3
            uint32 t0 = (uint32)__shfl((int)pk0, selA, 64);
            uint32 t1 = (uint32)__shfl((int)pk1, selA, 64);
            uint32 t2 = (uint32)__shfl((int)pk0, selB, 64);
            uint32 t3 = (uint32)__shfl((int)pk1, selB, 64);
            uint32 u0 = (uint32)__shfl((int)pk2, r16, 64);   // j16,17 from g'=0
            uint32 u1 = (uint32)__shfl((int)pk3, r16, 64);   // j18,19 from g'=0
            uint4 f;
            f.x = (g < 2) ? t0 : ((g == 2) ? u0 : 0u);
            f.y = (g < 2) ? t1 : ((g == 2) ? u1 : 0u);
            f.z = (g < 2) ? t2 : ((g == 2) ? 0x00003C00u : 0u);  // j20 = rest wt 1.0
            f.w = (g < 2) ? t3 : 0u;
            bpv[n] = f;
        }

        // ---- PV O^T[c][p] = sum_j V^T[c][j] * W^T[j][p] (K=32) ----
        #pragma unroll
        for (int m = 0; m < 4; m++) {
            uint4 a = (m == 0) ? apv0 : (m == 1) ? apv1 : (m == 2) ? apv2 : apv3;
            #pragma unroll
            for (int n = 0; n < 4; n++) {
                f4 o = (f4){0.f,0.f,0.f,0.f};
                o = __builtin_amdgcn_mfma_f32_16x16x32_f16(bch8(a), bch8(bpv[n]), o, 0, 0, 0);
                uint2 ov; ov.x = bcu(pkrtz(o[0], o[1])); ov.y = bcu(pkrtz(o[2], o[3]));
                if (mine[n])
                    *(uint2*)(lds + rowb[n] + m*32 + g*8) = ov;  // byte 2c: c = m*16+g*4..+3
            }
        }

        __builtin_amdgcn_s_setprio(0);

        // tile t complete: publish (O rows of its 64 pixels are final)
        __threadfence_block();
        if (lane == 0)
            __hip_atomic_store(&flags[t], 1, __ATOMIC_RELEASE, __HIP_MEMORY_SCOPE_WORKGROUP);
    }

    // self-service store: wait only for MY tile, then store own row (coalesced)
    while (__hip_atomic_load(&flags[mytile], __ATOMIC_ACQUIRE,
                             __HIP_MEMORY_SCOPE_WORKGROUP) == 0) {
        __builtin_amdgcn_s_sleep(1);
    }
    {
        const uint4* r4 = (const uint4*)(lds + tid * ROW_STRIDE);
        float* op = obase + tid;
        #pragma unroll
        for (int q = 0; q < 8; q++) {
            uint4 v = r4[q];
            h2 x = bch2(v.x), y = bch2(v.y), z = bch2(v.z), w = bch2(v.w);
            op[(size_t)(8*q+0) * HW] = (float)x[0];
            op[(size_t)(8*q+1) * HW] = (float)x[1];
            op[(size_t)(8*q+2) * HW] = (float)y[0];
            op[(size_t)(8*q+3) * HW] = (float)y[1];
            op[(size_t)(8*q+4) * HW] = (float)z[0];
            op[(size_t)(8*q+5) * HW] = (float)z[1];
            op[(size_t)(8*q+6) * HW] = (float)w[0];
            op[(size_t)(8*q+7) * HW] = (float)w[1];
        }
    }
}

extern "C" void kernel_launch(void* const* d_in, const int* in_sizes, int n_in,
                              void* d_out, int out_size, void* d_ws, size_t ws_size,
                              hipStream_t stream) {
    const float* content = (const float*)d_in[0];
    const int*   seg     = (const int*)d_in[1];
    const float* key     = (const float*)d_in[2];
    const float* val     = (const float*)d_in[3];
    float* out = (float*)d_out;
    unsigned char* ws = (unsigned char*)d_ws;

    prep_kernel<<<7, 256, 0, stream>>>(key, val, ws);

    (void)hipFuncSetAttribute((const void*)main_kernel,
                              hipFuncAttributeMaxDynamicSharedMemorySize, LDS_TOTAL);
    main_kernel<<<NPIX/BLK, BLK, LDS_TOTAL, stream>>>(content, seg, ws, out);
}